// Round 14
// baseline (91.665 us; speedup 1.0000x reference)
//
#include <hip/hip_runtime.h>
#include <math.h>

#define N 4096
#define FEPS 1e-7f
#define BLK 256
#define R 2                  // rows per lane
#define RPB (BLK * R)        // 512 rows per block
#define GB (N / RPB)         // 8 row-groups
#define JT 256               // j-chunks: grid = 8*256 = 2048 blocks = 8/CU = 32 waves/CU
#define CH (N / JT)          // 16 j's per block in LDS
#define N6 (N * 6)
#define RCH 4                // jt reduction chunks (stage-1)
#define JPC (JT / RCH)       // 64 jt-slices per chunk

// d_ws: part[jt][i*6+k] (JT*N*6 floats = 25.2 MB) | reduced4[RCH][N*6] (393 KB)
#define RED_OFF ((size_t)JT * N6)

// Main kernel: r12/r13 body unchanged; ONLY the grid split changed
// (JT 128->256). Rationale: every structure since r7 ran 1024 blocks =
// 16 waves/CU (half the slots); measured duty ~55-65% across r3/r4 and the
// ~275cy/body calibration. 2048 blocks = 32 waves/CU to hide exp2/rcp/LDS
// latency. j-record in LDS as 3 float4s (ds_read_b128); folds: K into atan,
// /4 into half-coords, union-eps split, log2(e) into conf. iou clamped to 1.0
// (fast-rcp overshoot on diagonal -> 0*inf = NaN, measured r2->r3).
// NOTE (r5/r6): no 2nd __launch_bounds__ arg — (256,4) forced VGPR=64, spilled.
__global__ __launch_bounds__(BLK) void ciou_attn_kernel(
        const float* __restrict__ x,
        float* __restrict__ part) {
    __shared__ float4 jv[CH * 3];
    const int tid = threadIdx.x;
    const int gb = blockIdx.x / JT;
    const int jt = blockIdx.x % JT;

    if (tid < CH) {
        int j = jt * CH + tid;
        const float* xj = x + (size_t)j * 5;
        float cf = xj[0], x1 = xj[1], y1 = xj[2], x2 = xj[3], y2 = xj[4];
        float w = x2 - x1, h = y2 - y1;
        jv[tid * 3 + 0] = make_float4(cf, x1, y1, x2);
        jv[tid * 3 + 1] = make_float4(y2, (x1 + x2) * 0.5f, (y1 + y2) * 0.5f, w);
        jv[tid * 3 + 2] = make_float4(h, w * h + 0.5f * FEPS,
                                      0.6366197723675814f * atanf(w / (h + FEPS)),
                                      cf * 1.2011224087864498f);
    }

    float rx1[R], ry1[R], rx2[R], ry2[R], rhx[R], rhy[R];
    float rw[R], rh[R], rareps[R], rat[R], rcf2[R];
#pragma unroll
    for (int r = 0; r < R; r++) {
        int i = gb * RPB + r * BLK + tid;
        const float* xi = x + (size_t)i * 5;
        float cf = xi[0], x1 = xi[1], y1 = xi[2], x2 = xi[3], y2 = xi[4];
        float w = x2 - x1, h = y2 - y1;
        rx1[r] = x1; ry1[r] = y1; rx2[r] = x2; ry2[r] = y2;
        rhx[r] = (x1 + x2) * 0.5f; rhy[r] = (y1 + y2) * 0.5f;
        rw[r] = w; rh[r] = h;
        rareps[r] = w * h + 0.5f * FEPS;
        rat[r] = 0.6366197723675814f * atanf(w / (h + FEPS));
        rcf2[r] = cf * 1.2011224087864498f;
    }

    __syncthreads();

    float sum[R], a0[R], a1[R], a2[R], a3[R], a4[R];
#pragma unroll
    for (int r = 0; r < R; r++) {
        sum[r] = 0.f; a0[r] = 0.f; a1[r] = 0.f; a2[r] = 0.f; a3[r] = 0.f; a4[r] = 0.f;
    }
    const float ONEP = 1.f + FEPS;

#pragma unroll 2
    for (int jj = 0; jj < CH; jj++) {
        float4 A = jv[jj * 3 + 0], B = jv[jj * 3 + 1], C = jv[jj * 3 + 2];
        float jcf = A.x, jx1 = A.y, jy1 = A.z, jx2 = A.w;
        float jy2 = B.x, jhx = B.y, jhy = B.z, jw = B.w;
        float jh = C.x, jareps = C.y, jat = C.z, jcf2 = C.w;
#pragma unroll
        for (int r = 0; r < R; r++) {
            float iwr = fminf(rx2[r], jx2) - fmaxf(rx1[r], jx1);
            float ihr = fminf(ry2[r], jy2) - fmaxf(ry1[r], jy1);
            float iw = fmaxf(iwr, 0.f);
            float ih = fmaxf(ihr, 0.f);
            float inter = iw * ih;
            float uni = (rareps[r] + jareps) - inter;
            float iou = fminf(inter * __builtin_amdgcn_rcpf(uni), 1.0f);
            float cw = (rw[r] + jw) - iwr;
            float chh = (rh[r] + jh) - ihr;
            float c2 = fmaf(cw, cw, fmaf(chh, chh, FEPS));
            float dx = jhx - rhx[r];
            float dy = jhy - rhy[r];
            float rho2 = fmaf(dx, dx, dy * dy);
            float da = jat - rat[r];
            float v = da * da;
            float den = (v - iou) + ONEP;
            float valpha = (v * v) * __builtin_amdgcn_rcpf(den);
            float ciou = iou - fmaf(rho2, __builtin_amdgcn_rcpf(c2), valpha);
            float e = __builtin_amdgcn_exp2f(ciou * (rcf2[r] * jcf2));
            sum[r] += e;
            a0[r] = fmaf(e, jcf, a0[r]);
            a1[r] = fmaf(e, jx1, a1[r]);
            a2[r] = fmaf(e, jy1, a2[r]);
            a3[r] = fmaf(e, jx2, a3[r]);
            a4[r] = fmaf(e, jy2, a4[r]);
        }
    }

#pragma unroll
    for (int r = 0; r < R; r++) {
        int i = gb * RPB + r * BLK + tid;
        float* p = part + (size_t)jt * N6 + (size_t)i * 6;
        p[0] = sum[r]; p[1] = a0[r]; p[2] = a1[r];
        p[3] = a2[r]; p[4] = a3[r]; p[5] = a4[r];
    }
}

// Stage 1: coalesced jt-reduction (measured r13: fixed the ~15us strided
// epilogue). Block (fb, ch): threads cover flat [fb*BLK, fb*BLK+BLK) of
// [0, N*6); each sums JPC jt-slices of chunk ch. 25 MB fully coalesced.
__global__ void reduce_kernel(const float* __restrict__ part,
                              float* __restrict__ reduced4) {
    int flat = (blockIdx.x % (N6 / BLK)) * BLK + threadIdx.x;
    int ch = blockIdx.x / (N6 / BLK);
    const float* p = part + (size_t)ch * JPC * N6 + flat;
    float s = 0.f;
#pragma unroll 8
    for (int t = 0; t < JPC; t++) s += p[(size_t)t * N6];
    reduced4[(size_t)ch * N6 + flat] = s;
}

// Stage 2: one thread per output element: sum RCH chunk-results, divide, sigmoid.
__global__ void epilogue_kernel(const float* __restrict__ x,
                                const float* __restrict__ gamma,
                                const float* __restrict__ reduced4,
                                float* __restrict__ out) {
    int idx = blockIdx.x * blockDim.x + threadIdx.x;
    if (idx >= N * 5) return;
    int i = idx / 5, c = idx % 5;
    float se = 0.f, a = 0.f;
#pragma unroll
    for (int ch = 0; ch < RCH; ch++) {
        se += reduced4[(size_t)ch * N6 + i * 6];
        a  += reduced4[(size_t)ch * N6 + i * 6 + 1 + c];
    }
    float xp = x[idx] * gamma[0] + a / se;
    out[idx] = 1.f / (1.f + expf(-xp));
}

extern "C" void kernel_launch(void* const* d_in, const int* in_sizes, int n_in,
                              void* d_out, int out_size, void* d_ws, size_t ws_size,
                              hipStream_t stream) {
    const float* x = (const float*)d_in[0];
    const float* gamma = (const float*)d_in[1];
    float* out = (float*)d_out;
    float* part = (float*)d_ws;
    float* reduced4 = (float*)d_ws + RED_OFF;

    ciou_attn_kernel<<<GB * JT, BLK, 0, stream>>>(x, part);
    reduce_kernel<<<(N6 / BLK) * RCH, BLK, 0, stream>>>(part, reduced4);
    epilogue_kernel<<<(N * 5 + 255) / 256, 256, 0, stream>>>(x, gamma, reduced4, out);
}

// Round 15
// 85.197 us; speedup vs baseline: 1.0759x; 1.0759x over previous
//
#include <hip/hip_runtime.h>
#include <math.h>

#define N 4096
#define FEPS 1e-7f
#define BLK 256
#define RPB BLK              // R=1: 256 rows per block
#define GB (N / RPB)         // 16 row-groups
#define JT 128               // grid = 16*128 = 2048 blocks; VGPR<=64 -> 8/CU = 32 waves/CU
#define CH (N / JT)          // 32 j's per block in LDS
#define N6 (N * 6)
#define RCH 4
#define JPC (JT / RCH)       // 32 jt-slices per reduce chunk

// d_ws: part[jt][i*6+k] (JT*N*6 floats = 12.6 MB) | reduced4[RCH][N*6] (393 KB)
#define RED_OFF ((size_t)JT * N6)

// R=1 row-per-lane. __launch_bounds__(256,8) forces VGPR=64: the lean body
// (~50 live regs) fits, giving 8 blocks/CU = 32 waves/CU — the occupancy test
// r14 couldn't run (its R=2 body was VGPR-capped at 16 waves/CU regardless of
// grid). r6's spill disaster was this same cap on a ~136-reg body; lesson:
// cap only when the body fits under it.
// j-record in LDS as 3 float4s (ds_read_b128). Folds: K=4/pi^2 into atan,
// rho2's /4 into half-coords, union-eps split, log2(e) into conf.
// iou clamped to 1.0 (fast-rcp overshoot on diagonal -> 0*inf = NaN, r2->r3).
__global__ __launch_bounds__(BLK, 8) void ciou_attn_kernel(
        const float* __restrict__ x,
        float* __restrict__ part) {
    __shared__ float4 jv[CH * 3];
    const int tid = threadIdx.x;
    const int gb = blockIdx.x / JT;
    const int jt = blockIdx.x % JT;

    if (tid < CH) {
        int j = jt * CH + tid;
        const float* xj = x + (size_t)j * 5;
        float cf = xj[0], x1 = xj[1], y1 = xj[2], x2 = xj[3], y2 = xj[4];
        float w = x2 - x1, h = y2 - y1;
        jv[tid * 3 + 0] = make_float4(cf, x1, y1, x2);
        jv[tid * 3 + 1] = make_float4(y2, (x1 + x2) * 0.5f, (y1 + y2) * 0.5f, w);
        jv[tid * 3 + 2] = make_float4(h, w * h + 0.5f * FEPS,
                                      0.6366197723675814f * atanf(w / (h + FEPS)),
                                      cf * 1.2011224087864498f);
    }

    // Per-lane row record (one row per lane).
    const int i = gb * RPB + tid;
    const float* xi = x + (size_t)i * 5;
    float cf0 = xi[0], rx1 = xi[1], ry1 = xi[2], rx2 = xi[3], ry2 = xi[4];
    float rwv = rx2 - rx1, rhv = ry2 - ry1;
    float rhx = (rx1 + rx2) * 0.5f, rhy = (ry1 + ry2) * 0.5f;
    float rareps = rwv * rhv + 0.5f * FEPS;
    float rat = 0.6366197723675814f * atanf(rwv / (rhv + FEPS));
    float rcf2 = cf0 * 1.2011224087864498f;

    __syncthreads();

    float sum = 0.f, a0 = 0.f, a1 = 0.f, a2 = 0.f, a3 = 0.f, a4 = 0.f;
    const float ONEP = 1.f + FEPS;

#pragma unroll 1
    for (int jj = 0; jj < CH; jj++) {
        float4 A = jv[jj * 3 + 0], B = jv[jj * 3 + 1], C = jv[jj * 3 + 2];
        float jcf = A.x, jx1 = A.y, jy1 = A.z, jx2 = A.w;
        float jy2 = B.x, jhx = B.y, jhy = B.z, jw = B.w;
        float jh = C.x, jareps = C.y, jat = C.z, jcf2 = C.w;

        float iwr = fminf(rx2, jx2) - fmaxf(rx1, jx1);
        float ihr = fminf(ry2, jy2) - fmaxf(ry1, jy1);
        float iw = fmaxf(iwr, 0.f);
        float ih = fmaxf(ihr, 0.f);
        float inter = iw * ih;
        float uni = (rareps + jareps) - inter;
        float iou = fminf(inter * __builtin_amdgcn_rcpf(uni), 1.0f);
        float cw = (rwv + jw) - iwr;
        float chh = (rhv + jh) - ihr;
        float c2 = fmaf(cw, cw, fmaf(chh, chh, FEPS));
        float dx = jhx - rhx;
        float dy = jhy - rhy;
        float rho2 = fmaf(dx, dx, dy * dy);
        float da = jat - rat;
        float v = da * da;
        float den = (v - iou) + ONEP;
        float valpha = (v * v) * __builtin_amdgcn_rcpf(den);
        float ciou = iou - fmaf(rho2, __builtin_amdgcn_rcpf(c2), valpha);
        float e = __builtin_amdgcn_exp2f(ciou * (rcf2 * jcf2));
        sum += e;
        a0 = fmaf(e, jcf, a0);
        a1 = fmaf(e, jx1, a1);
        a2 = fmaf(e, jy1, a2);
        a3 = fmaf(e, jx2, a3);
        a4 = fmaf(e, jy2, a4);
    }

    float* p = part + (size_t)jt * N6 + (size_t)i * 6;
    p[0] = sum; p[1] = a0; p[2] = a1; p[3] = a2; p[4] = a3; p[5] = a4;
}

// Stage 1: coalesced jt-reduction (r13-measured: ~4 us for 12.6 MB).
__global__ void reduce_kernel(const float* __restrict__ part,
                              float* __restrict__ reduced4) {
    int flat = (blockIdx.x % (N6 / BLK)) * BLK + threadIdx.x;
    int ch = blockIdx.x / (N6 / BLK);
    const float* p = part + (size_t)ch * JPC * N6 + flat;
    float s = 0.f;
#pragma unroll 8
    for (int t = 0; t < JPC; t++) s += p[(size_t)t * N6];
    reduced4[(size_t)ch * N6 + flat] = s;
}

// Stage 2: one thread per output element.
__global__ void epilogue_kernel(const float* __restrict__ x,
                                const float* __restrict__ gamma,
                                const float* __restrict__ reduced4,
                                float* __restrict__ out) {
    int idx = blockIdx.x * blockDim.x + threadIdx.x;
    if (idx >= N * 5) return;
    int i = idx / 5, c = idx % 5;
    float se = 0.f, a = 0.f;
#pragma unroll
    for (int ch = 0; ch < RCH; ch++) {
        se += reduced4[(size_t)ch * N6 + i * 6];
        a  += reduced4[(size_t)ch * N6 + i * 6 + 1 + c];
    }
    float xp = x[idx] * gamma[0] + a / se;
    out[idx] = 1.f / (1.f + expf(-xp));
}

extern "C" void kernel_launch(void* const* d_in, const int* in_sizes, int n_in,
                              void* d_out, int out_size, void* d_ws, size_t ws_size,
                              hipStream_t stream) {
    const float* x = (const float*)d_in[0];
    const float* gamma = (const float*)d_in[1];
    float* out = (float*)d_out;
    float* part = (float*)d_ws;
    float* reduced4 = (float*)d_ws + RED_OFF;

    ciou_attn_kernel<<<GB * JT, BLK, 0, stream>>>(x, part);
    reduce_kernel<<<(N6 / BLK) * RCH, BLK, 0, stream>>>(part, reduced4);
    epilogue_kernel<<<(N * 5 + 255) / 256, 256, 0, stream>>>(x, gamma, reduced4, out);
}